// Round 6
// baseline (275.903 us; speedup 1.0000x reference)
//
#include <hip/hip_runtime.h>

// ---------------------------------------------------------------------------
// PWC-Net decoder level (B=16, C=48, H=64, W=128) — MFMA implicit-GEMM convs.
// d_out = [flow 16*2*64*128][feat_out 16*269*64*128] (f32)
// Reference out-channel order: [c4 0..15][c3 16..39][c2 40..87][c1 88..135]
//                    [corr 136..216][feat1 217..264][upflow 265..266][upfeat 267..268]
// featb (bf16 [B][H][W][272]) uses a PERMUTED channel order for aligned writes:
//   [c4][c3][c2][c1][f1 136..183][corr 184..264][upflow][upfeat][pad 269..271]
// Permutation baked into weight repack (featb2ref).
// Conv blocks: 4 output rows x 64 px (M=256), 2 waves x 8 M-frags each,
// K-chunks of 32ch; LDS = 6 staged rows x 68 slots + weight slab (<=54KB).
// ---------------------------------------------------------------------------

#define DEVFN __device__ __forceinline__

constexpr int B = 16, H = 64, W = 128, HW = H * W;
constexpr int CF = 48;
constexpr int PFC = 217;
constexpr int H2 = 32, W2 = 64, HW2 = H2 * W2;
constexpr int FC = 269;
constexpr int FCP = 272;
constexpr int FLOW_ELEMS = B * 2 * HW;

constexpr int OFF_CORR = 136, OFF_F1 = 217, OFF_UF = 265, OFF_UPFEAT = 267;
constexpr int FB_F1 = 136, FB_CORR = 184;

// ws layout (bytes)
constexpr size_t WS_ZEROS = 0;
constexpr size_t WS_FEATB = 256;
constexpr size_t FEATB_BYTES = (size_t)B * HW * FCP * 2;
constexpr size_t WS_WARPEDH = WS_FEATB + FEATB_BYTES;
constexpr size_t WARPEDH_BYTES = (size_t)3 * B * HW * 16 * 2;
constexpr size_t WS_PART = WS_WARPEDH + WARPEDH_BYTES;
constexpr size_t PART_BYTES = (size_t)7 * B * 2 * HW * 4;
constexpr size_t WS_WB = WS_PART + PART_BYTES;

typedef short bf16x8 __attribute__((ext_vector_type(8)));
typedef float f32x4 __attribute__((ext_vector_type(4)));
typedef _Float16 h16x2 __attribute__((ext_vector_type(2)));
typedef _Float16 h16x8 __attribute__((ext_vector_type(8)));

DEVFN float leaky(float x) { return x >= 0.f ? x : 0.1f * x; }

DEVFN unsigned short f2b(float f) {  // RNE f32 -> bf16
  unsigned int u = __float_as_uint(f);
  u += 0x7FFFu + ((u >> 16) & 1u);
  return (unsigned short)(u >> 16);
}

DEVFN void gload16(const void* g, void* l) {
  __builtin_amdgcn_global_load_lds(
      (const __attribute__((address_space(1))) void*)g,
      (__attribute__((address_space(3))) void*)l, 16, 0, 0);
}

DEVFN int featb2ref(int p) {
  if (p >= FB_F1 && p < FB_CORR) return OFF_F1 + (p - FB_F1);
  if (p >= FB_CORR && p < 265) return OFF_CORR + (p - FB_CORR);
  return p;
}

// ---------- fused prep: weight repack (all 5) + dcf partials + dflow -------
// blocks [0,1188): repack; [1188,4772): dcf partials; [4772,5796): dflow.
__global__ __launch_bounds__(256) void k_prep(
    const float* __restrict__ w1, const float* __restrict__ w2,
    const float* __restrict__ w3, const float* __restrict__ w4,
    const float* __restrict__ w5,
    unsigned short* __restrict__ wb1, unsigned short* __restrict__ wb2,
    unsigned short* __restrict__ wb3, unsigned short* __restrict__ wb4,
    unsigned short* __restrict__ wb5, unsigned short* __restrict__ zeros,
    const float* __restrict__ pfeat, const float* __restrict__ wup,
    const float* __restrict__ pflow, const float* __restrict__ wuf,
    const float* __restrict__ buf_, float* __restrict__ partial,
    float* __restrict__ feat, unsigned short* __restrict__ featb) {
  __shared__ float wl[1024];
  __shared__ float red[2048];
  const int tid = threadIdx.x;
  const int gblk = blockIdx.x;
  if (gblk < 1188) {
    // ---------------- weight repack ----------------
    if (gblk == 0 && tid < 32) zeros[tid] = 0;
    const float* w;
    unsigned short* wb;
    int CIN, COUT, COUTP, IN_OFF, rbase;
    if (gblk < 270)       { w = w1; wb = wb1; CIN = 133; COUT = 48; COUTP = 48; IN_OFF = 136; rbase = 0; }
    else if (gblk < 594)  { w = w2; wb = wb2; CIN = 181; COUT = 48; COUTP = 48; IN_OFF = 88;  rbase = 270; }
    else if (gblk < 882)  { w = w3; wb = wb3; CIN = 229; COUT = 24; COUTP = 32; IN_OFF = 40;  rbase = 594; }
    else if (gblk < 1026) { w = w4; wb = wb4; CIN = 253; COUT = 16; COUTP = 16; IN_OFF = 16;  rbase = 882; }
    else                  { w = w5; wb = wb5; CIN = 269; COUT = 2;  COUTP = 16; IN_OFF = 0;   rbase = 1026; }
    int e = (gblk - rbase) * 256 + tid;
    int nchunk = (CIN + 31) >> 5;
    int TOT = nchunk * 9 * COUTP * 32;
    if (e >= TOT) return;
    int j = e & 7, qpos = (e >> 3) & 3;
    int row = e >> 5;
    int co = row % COUTP;
    int tapch = row / COUTP;
    int tap = tapch % 9, ch = tapch / 9;
    int k = ch * 32 + ((qpos ^ ((co >> 1) & 3)) << 3) + j;
    float v = 0.f;
    if (co < COUT && k < CIN) {
      int ci = featb2ref(IN_OFF + k) - IN_OFF;
      v = w[(co * CIN + ci) * 9 + tap];
    }
    wb[e] = f2b(v);
    return;
  }
  if (gblk >= 4772) {
    // ---------------- deconv4x4 s2 on prev_flow ----------------
    int t = (gblk - 4772) * 256 + tid;
    if (t >= B * 2 * HW) return;
    int x = t % W, y = (t / W) % H, co = (t / HW) % 2, b = t / (2 * HW);
    float acc = buf_[co];
    int ky0 = ((y & 1) == 0) ? 1 : 0;
    int kx0 = ((x & 1) == 0) ? 1 : 0;
#pragma unroll
    for (int kyi = 0; kyi < 2; ++kyi) {
      int ky = ky0 + 2 * kyi;
      int iy = (y + 1 - ky) >> 1;
      if (iy < 0 || iy >= H2) continue;
#pragma unroll
      for (int kxi = 0; kxi < 2; ++kxi) {
        int kx = kx0 + 2 * kxi;
        int ix = (x + 1 - kx) >> 1;
        if (ix < 0 || ix >= W2) continue;
#pragma unroll
        for (int ci = 0; ci < 2; ++ci)
          acc += pflow[(b * 2 + ci) * HW2 + iy * W2 + ix] *
                 wuf[((ci * 2 + co) * 4 + ky) * 4 + kx];
      }
    }
    int pix = (b * H + y) * W + x;
    feat[(b * FC + OFF_UF + co) * HW + y * W + x] = acc;
    featb[pix * FCP + OFF_UF + co] = f2b(acc);
    if (co == 0) {
      featb[pix * FCP + 269] = 0;
      featb[pix * FCP + 270] = 0;
      featb[pix * FCP + 271] = 0;
    }
    return;
  }
  // ---------------- deconv4x4 s2 on prev_feat: partials ----------------
  int blk = gblk - 1188;
  int chunk = blk % 7, t2 = blk / 7;
  int y2 = t2 % H2, b = t2 / H2;
  int ch0 = chunk * 32;
  for (int i = tid; i < 1024; i += 256) {
    int ci = ch0 + (i >> 5);
    wl[i] = (ci < PFC) ? wup[ci * 32 + (i & 31)] : 0.f;
  }
  __syncthreads();
  int x2 = tid & 63, cg = tid >> 6;
  float acc[8];
#pragma unroll
  for (int v = 0; v < 8; ++v) acc[v] = 0.f;
#pragma unroll 1
  for (int k = 0; k < 8; ++k) {
    int cil = cg * 8 + k;
    int ci = ch0 + cil;
    bool cv = ci < PFC;
    const float* src = pfeat + ((size_t)b * PFC + ci) * HW2;
    float iv[3][3];
#pragma unroll
    for (int dy = -1; dy <= 1; ++dy)
#pragma unroll
      for (int dx = -1; dx <= 1; ++dx) {
        int iy = y2 + dy, ix = x2 + dx;
        float v = 0.f;
        if (cv && iy >= 0 && iy < H2 && ix >= 0 && ix < W2) v = src[iy * W2 + ix];
        iv[dy + 1][dx + 1] = v;
      }
    const float* wc = &wl[cil * 32];
#pragma unroll
    for (int co = 0; co < 2; ++co)
#pragma unroll
      for (int ry = 0; ry < 2; ++ry)
#pragma unroll
        for (int rx = 0; rx < 2; ++rx) {
          float s = acc[co * 4 + ry * 2 + rx];
#pragma unroll
          for (int dy = ry - 1; dy <= ry; ++dy) {
            int ky = 1 + ry - 2 * dy;
#pragma unroll
            for (int dx = rx - 1; dx <= rx; ++dx) {
              int kx = 1 + rx - 2 * dx;
              s += iv[dy + 1][dx + 1] * wc[co * 16 + ky * 4 + kx];
            }
          }
          acc[co * 4 + ry * 2 + rx] = s;
        }
  }
#pragma unroll
  for (int v = 0; v < 8; ++v) red[(cg * 64 + x2) * 8 + v] = acc[v];
  __syncthreads();
  for (int idx = tid; idx < 512; idx += 256) {
    int x2b = idx & 63, vi = idx >> 6;
    float s = red[(0 + x2b) * 8 + vi] + red[(64 + x2b) * 8 + vi] +
              red[(128 + x2b) * 8 + vi] + red[(192 + x2b) * 8 + vi];
    int co = vi >> 2, ry = (vi >> 1) & 1, rx = vi & 1;
    partial[(size_t)chunk * (B * 2 * HW) + (size_t)(b * 2 + co) * HW +
            (2 * y2 + ry) * W + (2 * x2b + rx)] = s;
  }
}

// --------- fused: finalize upfeat (blk<1024) + backwarp (rest) -------------
__global__ __launch_bounds__(256) void k_fin_backwarp(
    const float* __restrict__ partial, const float* __restrict__ bup,
    const float* __restrict__ feat2, float* __restrict__ feat,
    unsigned short* __restrict__ featb, unsigned short* __restrict__ warpedh) {
  int tid = threadIdx.x;
  if (blockIdx.x < 1024) {
    int t = blockIdx.x * 256 + tid;
    float s = 0.f;
#pragma unroll
    for (int c = 0; c < 7; ++c) s += partial[(size_t)c * (B * 2 * HW) + t];
    int rem = t % HW;
    int co = (t / HW) & 1;
    int b = t / (2 * HW);
    s += bup[co];
    feat[((size_t)b * FC + OFF_UPFEAT + co) * HW + rem] = s;
    featb[((size_t)(b * H) * W + rem) * FCP + OFF_UPFEAT + co] = f2b(s);
    return;
  }
  int t = (blockIdx.x - 1024) * 256 + tid;
  if (t >= B * HW) return;
  int x = t % W, y = (t / W) % H, b = t / HW;
  const float SX = 1.25f * (float)W / (float)(W - 1);
  const float SY = 1.25f * (float)H / (float)(H - 1);
  float fx = feat[(b * FC + OFF_UF + 0) * HW + y * W + x];
  float fy = feat[(b * FC + OFF_UF + 1) * HW + y * W + x];
  float px = (float)x + fx * SX;
  float py = (float)y + fy * SY;
  float x0f = floorf(px), y0f = floorf(py);
  int ix0 = (int)x0f, iy0 = (int)y0f;
  float wx1 = px - x0f, wx0 = 1.f - wx1;
  float wy1 = py - y0f, wy0 = 1.f - wy1;
  bool vx0 = (ix0 >= 0) & (ix0 < W), vx1 = (ix0 + 1 >= 0) & (ix0 + 1 < W);
  bool vy0 = (iy0 >= 0) & (iy0 < H), vy1 = (iy0 + 1 >= 0) & (iy0 + 1 < H);
  float w00 = (vx0 && vy0) ? wx0 * wy0 : 0.f;
  float w01 = (vx1 && vy0) ? wx1 * wy0 : 0.f;
  float w10 = (vx0 && vy1) ? wx0 * wy1 : 0.f;
  float w11 = (vx1 && vy1) ? wx1 * wy1 : 0.f;
  float wsum = w00 + w01 + w10 + w11;
  float m = wsum > 0.999f ? 1.f : 0.f;
  w00 *= m; w01 *= m; w10 *= m; w11 *= m;
  int cx0 = min(max(ix0, 0), W - 1), cx1 = min(max(ix0 + 1, 0), W - 1);
  int cy0 = min(max(iy0, 0), H - 1), cy1 = min(max(iy0 + 1, 0), H - 1);
  const float* s = feat2 + b * CF * HW;
  int o00 = cy0 * W + cx0, o01 = cy0 * W + cx1, o10 = cy1 * W + cx0, o11 = cy1 * W + cx1;
#pragma unroll 1
  for (int chunk = 0; chunk < 3; ++chunk) {
    h16x8 out0, out1;
#pragma unroll
    for (int k = 0; k < 16; ++k) {
      const float* sc = s + (chunk * 16 + k) * HW;
      float v = w00 * sc[o00] + w01 * sc[o01] + w10 * sc[o10] + w11 * sc[o11];
      if (k < 8) out0[k & 7] = (_Float16)v;
      else       out1[k & 7] = (_Float16)v;
    }
    h16x8* dst = (h16x8*)(warpedh + ((size_t)chunk * B * HW + t) * 16);
    dst[0] = out0;
    dst[1] = out1;
  }
}

// --------------------------- correlation + leaky ---------------------------
// grid = B*H*2 (XCD-swizzled): each block does ONE dy-half (half = dy 0..4 or
// 5..8) for one (b,y) row. 256 thr: px = tid>>1, h = tid&1 (channel half).
__global__ __launch_bounds__(256) void k_corr(const float* __restrict__ f1,
                                              const unsigned short* __restrict__ warpedh,
                                              const unsigned short* __restrict__ zeros,
                                              float* __restrict__ feat,
                                              unsigned short* __restrict__ featb) {
  __shared__ __align__(16) unsigned short lds[5 * 136 * 16];
  const int swz = ((blockIdx.x & 7) << 8) | (blockIdx.x >> 3);
  const int half = swz & 1;
  const int y = (swz >> 1) & 63, b = swz >> 7;
  const int tid = threadIdx.x;
  const int px = tid >> 1, h = tid & 1;
  const int lane = tid & 63, wv = tid >> 6;
  const int pix = (b * H + y) * W + px;
  const h16x8* hp = (const h16x8*)lds;
  char* ldsc = (char*)lds;
  const float inv = 1.f / 48.f;

  const int R = half ? 4 : 5;
  const int dybase = half ? 5 : 0;
  const int ND = R * 9;
  float acc[45];
#pragma unroll
  for (int d = 0; d < 45; ++d) acc[d] = 0.f;
#pragma unroll 1
  for (int chunk = 0; chunk < 3; ++chunk) {
    __syncthreads();
    const int NQ = R * 136 * 2;
    for (int q0 = 0; q0 < NQ; q0 += 256) {
      int q = q0 + tid;
      if (q < NQ) {
        int pr = q >> 1, u = q & 1;
        int r = pr / 136, p = pr - r * 136;
        int sw = (p >> 2) & 1;
        int yy = y + dybase + r - 4, xx = p - 4;
        const unsigned short* src = zeros;
        if (yy >= 0 && yy < H && xx >= 0 && xx < W)
          src = warpedh + (((size_t)chunk * B * H + b * H + yy) * W + xx) * 16 +
                (u ^ sw) * 8;
        gload16(src, ldsc + (size_t)q0 * 16 + wv * 1024 + lane * 16);
      }
    }
    float av[8];
    const int c0 = chunk * 16 + h * 8;
#pragma unroll
    for (int j = 0; j < 8; ++j)
      av[j] = f1[((size_t)b * CF + c0 + j) * HW + y * W + px];
    h16x2 fh[4];
#pragma unroll
    for (int j = 0; j < 4; ++j) {
      fh[j][0] = (_Float16)av[2 * j];
      fh[j][1] = (_Float16)av[2 * j + 1];
    }
    asm volatile("s_waitcnt vmcnt(0)" ::: "memory");
    __syncthreads();
    if (half == 0) {  // f1 copies done by the half-0 block only
#pragma unroll
      for (int j = 0; j < 8; ++j)
        feat[((size_t)b * FC + OFF_F1 + c0 + j) * HW + y * W + px] = av[j];
      uint4 qv;
      qv.x = (unsigned)f2b(av[0]) | ((unsigned)f2b(av[1]) << 16);
      qv.y = (unsigned)f2b(av[2]) | ((unsigned)f2b(av[3]) << 16);
      qv.z = (unsigned)f2b(av[4]) | ((unsigned)f2b(av[5]) << 16);
      qv.w = (unsigned)f2b(av[6]) | ((unsigned)f2b(av[7]) << 16);
      *(uint4*)(featb + (size_t)pix * FCP + FB_F1 + c0) = qv;
    }
#pragma unroll
    for (int dy = 0; dy < 5; ++dy) {
      if (dy < R) {
#pragma unroll
        for (int dx = 0; dx < 9; ++dx) {
          int p = px + dx;
          int sw = (p >> 2) & 1;
          h16x8 v = hp[((dy * 136 + p) << 1) | (h ^ sw)];
          float a = acc[dy * 9 + dx];
          a = __builtin_amdgcn_fdot2((h16x2){v[0], v[1]}, fh[0], a, false);
          a = __builtin_amdgcn_fdot2((h16x2){v[2], v[3]}, fh[1], a, false);
          a = __builtin_amdgcn_fdot2((h16x2){v[4], v[5]}, fh[2], a, false);
          a = __builtin_amdgcn_fdot2((h16x2){v[6], v[7]}, fh[3], a, false);
          acc[dy * 9 + dx] = a;
        }
      }
    }
  }
#pragma unroll
  for (int d = 0; d < 45; ++d) {
    if (d < ND) {
      float s = acc[d] + __shfl_xor(acc[d], 1);
      acc[d] = leaky(s * inv);
    }
  }
  if (h == 0) {
#pragma unroll
    for (int d = 0; d < 45; ++d)
      if (d < ND)
        feat[((size_t)b * FC + OFF_CORR + dybase * 9 + d) * HW + y * W + px] = acc[d];
  } else {
    unsigned short* fb = featb + (size_t)pix * FCP + FB_CORR + dybase * 9;
    if (half == 0) {  // pos 184..228: 5 x uint4 + 5 scalars
#pragma unroll
      for (int g = 0; g < 5; ++g) {
        uint4 qv;
        qv.x = (unsigned)f2b(acc[8 * g + 0]) | ((unsigned)f2b(acc[8 * g + 1]) << 16);
        qv.y = (unsigned)f2b(acc[8 * g + 2]) | ((unsigned)f2b(acc[8 * g + 3]) << 16);
        qv.z = (unsigned)f2b(acc[8 * g + 4]) | ((unsigned)f2b(acc[8 * g + 5]) << 16);
        qv.w = (unsigned)f2b(acc[8 * g + 6]) | ((unsigned)f2b(acc[8 * g + 7]) << 16);
        *(uint4*)(fb + 8 * g) = qv;
      }
#pragma unroll
      for (int d = 40; d < 45; ++d) fb[d] = f2b(acc[d]);
    } else {  // pos 229..264: 3 scalars + 4 x uint4 + 1 scalar
      fb[0] = f2b(acc[0]);
      fb[1] = f2b(acc[1]);
      fb[2] = f2b(acc[2]);
#pragma unroll
      for (int g = 0; g < 4; ++g) {
        uint4 qv;
        qv.x = (unsigned)f2b(acc[3 + 8 * g + 0]) | ((unsigned)f2b(acc[3 + 8 * g + 1]) << 16);
        qv.y = (unsigned)f2b(acc[3 + 8 * g + 2]) | ((unsigned)f2b(acc[3 + 8 * g + 3]) << 16);
        qv.z = (unsigned)f2b(acc[3 + 8 * g + 4]) | ((unsigned)f2b(acc[3 + 8 * g + 5]) << 16);
        qv.w = (unsigned)f2b(acc[3 + 8 * g + 6]) | ((unsigned)f2b(acc[3 + 8 * g + 7]) << 16);
        *(uint4*)(fb + 3 + 8 * g) = qv;
      }
      fb[35] = f2b(acc[35]);
    }
  }
}

// --------------------- conv3x3 + bias + leaky via MFMA ---------------------
// Block = 4 output rows x 64 px (M=256). 2 waves: wave wv -> output rows
// {y0+2wv, y0+2wv+1}, 8 M-frags (2 rows x 4 x-frags), all NF N-frags.
// LDS: 6 staged rows x 68 slots x 32ch + weight slab.
template <int CIN, int NCHUNK, int COUT, int COUTP, int IN_OFF, int OUT_OFF, bool TO_FLOW>
__global__ __launch_bounds__(128) void k_conv_mfma(
    const unsigned short* __restrict__ featb, const unsigned short* __restrict__ wb,
    const float* __restrict__ bias, const unsigned short* __restrict__ zeros,
    float* __restrict__ fout, unsigned short* __restrict__ bout) {
  constexpr int NF = COUTP / 16;
  constexpr int ROWPX = 68;
  constexpr int IN_ELE = 6 * ROWPX * 32;      // ushorts (13056)
  constexpr int W_SLAB = 9 * COUTP * 32;      // ushorts per chunk
  constexpr int NWI = (W_SLAB * 2) / 1024;    // weight gloads per chunk
  constexpr int CLIM = 264 - IN_OFF;
  constexpr int ROWB = ROWPX * 32;            // ushorts per staged row

  __shared__ unsigned short lds[IN_ELE + W_SLAB];

  const int swz = ((blockIdx.x & 7) << 6) | (blockIdx.x >> 3);  // 512 blocks
  const int xh = swz & 1, yt = (swz >> 1) & 15, b = swz >> 5;
  const int y0 = yt * 4, x0 = xh * 64;
  const int lane = threadIdx.x & 63, wv = threadIdx.x >> 6;
  const int arow = lane & 15, aslc = lane >> 4;

  // ---- input staging descriptors: 15 per wave (i = wv + 2t; 30 total) ----
  const unsigned short* gp[15];
  int c8a[15];
  int lofs[15];
  bool a4[15];
#pragma unroll
  for (int t = 0; t < 15; ++t) {
    int i = wv + 2 * t;
    int r = i / 5, seg = i % 5;
    int sbase = (seg < 4) ? seg * 16 : 64;
    int slot = sbase + (lane >> 2);
    int sub8 = ((lane & 3) ^ ((slot >> 1) & 3)) << 3;
    int yy = y0 + r - 1, xx = x0 + slot - 1;
    lofs[t] = (r * ROWPX + sbase) * 64;       // LDS byte offset (wave-uniform)
    a4[t] = (seg == 4);
    gp[t] = zeros; c8a[t] = 1 << 20;
    if (yy >= 0 && yy < H && xx >= 0 && xx < W) {
      gp[t] = featb + ((b * H + yy) * W + xx) * FCP + IN_OFF + sub8;
      c8a[t] = sub8;
    }
  }

  // ---- LDS read offsets (ushort units) ----
  int a_off[4][3];
#pragma unroll
  for (int xf = 0; xf < 4; ++xf)
#pragma unroll
    for (int kx = 0; kx < 3; ++kx) {
      int slot = xf * 16 + arow + kx;
      a_off[xf][kx] = (2 * wv) * ROWB + slot * 32 +
                      ((aslc ^ ((slot >> 1) & 3)) << 3);
    }
  int b_off[NF];
#pragma unroll
  for (int nf = 0; nf < NF; ++nf) {
    int co = nf * 16 + arow;
    b_off[nf] = IN_ELE + co * 32 + ((aslc ^ ((co >> 1) & 3)) << 3);
  }

  f32x4 acc[2][4][NF];
#pragma unroll
  for (int r = 0; r < 2; ++r)
#pragma unroll
    for (int xf = 0; xf < 4; ++xf)
#pragma unroll
      for (int nf = 0; nf < NF; ++nf) acc[r][xf][nf] = (f32x4){0.f, 0.f, 0.f, 0.f};

  char* ldsc = (char*)lds;

  for (int ch = 0; ch < NCHUNK; ++ch) {
    const int ci0 = ch * 32;
    __syncthreads();
#pragma unroll
    for (int t = 0; t < 15; ++t) {
      if (!a4[t] || lane < 16) {
        const unsigned short* g = (c8a[t] + ci0 <= CLIM) ? gp[t] + ci0 : zeros;
        gload16(g, ldsc + lofs[t]);
      }
    }
    for (int wi = wv; wi < NWI; wi += 2)
      gload16(wb + (size_t)ch * W_SLAB + wi * 512 + lane * 8,
              ldsc + IN_ELE * 2 + wi * 1024);
    asm volatile("s_waitcnt vmcnt(0)" ::: "memory");
    __syncthreads();
#pragma unroll
    for (int ky = 0; ky < 3; ++ky) {
#pragma unroll
      for (int kx = 0; kx < 3; ++kx) {
        bf16x8 afr[2][4];
#pragma unroll
        for (int r = 0; r < 2; ++r)
#pragma unroll
          for (int xf = 0; xf < 4; ++xf)
            afr[r][xf] = *(const bf16x8*)(lds + a_off[xf][kx] + (r + ky) * ROWB);
#pragma unroll
        for (int nf = 0; nf < NF; ++nf) {
          bf16x8 bfr = *(const bf16x8*)(lds + b_off[nf] + (ky * 3 + kx) * (COUTP * 32));
#pragma unroll
          for (int r = 0; r < 2; ++r)
#pragma unroll
            for (int xf = 0; xf < 4; ++xf)
              acc[r][xf][nf] = __builtin_amdgcn_mfma_f32_16x16x32_bf16(
                  afr[r][xf], bfr, acc[r][xf][nf], 0, 0, 0);
        }
      }
    }
  }

  // ---- epilogue ----
  const int dcol = lane & 15;
#pragma unroll
  for (int nf = 0; nf < NF; ++nf) {
    int co = nf * 16 + dcol;
    if (co < COUT) {
      float bv = bias[co];
#pragma unroll
      for (int r = 0; r < 2; ++r) {
        int yout = y0 + 2 * wv + r;
#pragma unroll
        for (int xf = 0; xf < 4; ++xf) {
#pragma unroll
          for (int rr = 0; rr < 4; ++rr) {
            int px = x0 + xf * 16 + (lane >> 4) * 4 + rr;
            float v = leaky(acc[r][xf][nf][rr] + bv);
            if constexpr (TO_FLOW) {
              fout[(b * 2 + co) * HW + yout * W + px] = v;
            } else {
              fout[(b * FC + OUT_OFF + co) * HW + yout * W + px] = v;
              bout[((b * H + yout) * W + px) * FCP + OUT_OFF + co] = f2b(v);
            }
          }
        }
      }
    }
  }
}

// ---------------------------------------------------------------------------
extern "C" void kernel_launch(void* const* d_in, const int* in_sizes, int n_in,
                              void* d_out, int out_size, void* d_ws, size_t ws_size,
                              hipStream_t stream) {
  (void)in_sizes; (void)n_in; (void)out_size; (void)ws_size;
  const float* feat_1 = (const float*)d_in[0];
  const float* feat_2 = (const float*)d_in[1];
  const float* prev_flow = (const float*)d_in[2];
  const float* prev_feat = (const float*)d_in[3];
  const float* w1 = (const float*)d_in[4];
  const float* b1 = (const float*)d_in[5];
  const float* w2 = (const float*)d_in[6];
  const float* b2 = (const float*)d_in[7];
  const float* w3 = (const float*)d_in[8];
  const float* b3 = (const float*)d_in[9];
  const float* w4 = (const float*)d_in[10];
  const float* b4 = (const float*)d_in[11];
  const float* w5 = (const float*)d_in[12];
  const float* b5 = (const float*)d_in[13];
  const float* w_upflow = (const float*)d_in[14];
  const float* b_upflow = (const float*)d_in[15];
  const float* w_upfeat = (const float*)d_in[16];
  const float* b_upfeat = (const float*)d_in[17];

  float* out = (float*)d_out;
  float* feat = out + FLOW_ELEMS;

  char* ws = (char*)d_ws;
  unsigned short* zeros = (unsigned short*)(ws + WS_ZEROS);
  unsigned short* featb = (unsigned short*)(ws + WS_FEATB);
  unsigned short* warpedh = (unsigned short*)(ws + WS_WARPEDH);
  float* partial = (float*)(ws + WS_PART);
  unsigned short* wb1 = (unsigned short*)(ws + WS_WB);
  unsigned short* wb2 = wb1 + 5 * 9 * 48 * 32;
  unsigned short* wb3 = wb2 + 6 * 9 * 48 * 32;
  unsigned short* wb4 = wb3 + 8 * 9 * 32 * 32;
  unsigned short* wb5 = wb4 + 8 * 9 * 16 * 32;

  k_prep<<<1188 + 3584 + 1024, 256, 0, stream>>>(
      w1, w2, w3, w4, w5, wb1, wb2, wb3, wb4, wb5, zeros,
      prev_feat, w_upfeat, prev_flow, w_upflow, b_upflow, partial, feat, featb);
  k_fin_backwarp<<<1024 + 512, 256, 0, stream>>>(partial, b_upfeat, feat_2,
                                                 feat, featb, warpedh);
  k_corr<<<B * H * 2, 256, 0, stream>>>(feat_1, warpedh, zeros, feat, featb);

  k_conv_mfma<133, 5, 48, 48, 136, 88, false><<<512, 128, 0, stream>>>(featb, wb1, b1, zeros, feat, featb);
  k_conv_mfma<181, 6, 48, 48, 88, 40, false><<<512, 128, 0, stream>>>(featb, wb2, b2, zeros, feat, featb);
  k_conv_mfma<229, 8, 24, 32, 40, 16, false><<<512, 128, 0, stream>>>(featb, wb3, b3, zeros, feat, featb);
  k_conv_mfma<253, 8, 16, 16, 16, 0, false><<<512, 128, 0, stream>>>(featb, wb4, b4, zeros, feat, featb);
  k_conv_mfma<269, 9, 2, 16, 0, 0, true><<<512, 128, 0, stream>>>(featb, wb5, b5, zeros, out, nullptr);
}

// Round 10
// 236.829 us; speedup vs baseline: 1.1650x; 1.1650x over previous
//
#include <hip/hip_runtime.h>

// ---------------------------------------------------------------------------
// PWC-Net decoder level (B=16, C=48, H=64, W=128) — MFMA implicit-GEMM convs.
// d_out = [flow 16*2*64*128][feat_out 16*269*64*128] (f32)
// Reference out-channel order: [c4 0..15][c3 16..39][c2 40..87][c1 88..135]
//                    [corr 136..216][feat1 217..264][upflow 265..266][upfeat 267..268]
// featb (bf16 [B][H][W][272]) PERMUTED: [c4][c3][c2][c1][f1 136..183]
//   [corr 184..264][upflow][upfeat][pad 269..271]; baked into weight repack.
// KNOWN-GOOD COMPOSITION: conv = r5 (247.7us, passed); prep/corr/fin = r6
// (passed). The r7-r9 reg-staged pipeline raced (unresolved) and is dropped.
// ---------------------------------------------------------------------------

#define DEVFN __device__ __forceinline__

constexpr int B = 16, H = 64, W = 128, HW = H * W;
constexpr int CF = 48;
constexpr int PFC = 217;
constexpr int H2 = 32, W2 = 64, HW2 = H2 * W2;
constexpr int FC = 269;
constexpr int FCP = 272;
constexpr int FLOW_ELEMS = B * 2 * HW;

constexpr int OFF_CORR = 136, OFF_F1 = 217, OFF_UF = 265, OFF_UPFEAT = 267;
constexpr int FB_F1 = 136, FB_CORR = 184;

// ws layout (bytes)
constexpr size_t WS_ZEROS = 0;
constexpr size_t WS_FEATB = 256;
constexpr size_t FEATB_BYTES = (size_t)B * HW * FCP * 2;
constexpr size_t WS_WARPEDH = WS_FEATB + FEATB_BYTES;
constexpr size_t WARPEDH_BYTES = (size_t)3 * B * HW * 16 * 2;
constexpr size_t WS_PART = WS_WARPEDH + WARPEDH_BYTES;
constexpr size_t PART_BYTES = (size_t)7 * B * 2 * HW * 4;
constexpr size_t WS_WB = WS_PART + PART_BYTES;

typedef short bf16x8 __attribute__((ext_vector_type(8)));
typedef float f32x4 __attribute__((ext_vector_type(4)));
typedef _Float16 h16x2 __attribute__((ext_vector_type(2)));
typedef _Float16 h16x8 __attribute__((ext_vector_type(8)));

DEVFN float leaky(float x) { return x >= 0.f ? x : 0.1f * x; }

DEVFN unsigned short f2b(float f) {  // RNE f32 -> bf16
  unsigned int u = __float_as_uint(f);
  u += 0x7FFFu + ((u >> 16) & 1u);
  return (unsigned short)(u >> 16);
}

DEVFN void gload16(const void* g, void* l) {
  __builtin_amdgcn_global_load_lds(
      (const __attribute__((address_space(1))) void*)g,
      (__attribute__((address_space(3))) void*)l, 16, 0, 0);
}

DEVFN int featb2ref(int p) {
  if (p >= FB_F1 && p < FB_CORR) return OFF_F1 + (p - FB_F1);
  if (p >= FB_CORR && p < 265) return OFF_CORR + (p - FB_CORR);
  return p;
}

// ---------- fused prep: weight repack (all 5) + dcf partials + dflow -------
__global__ __launch_bounds__(256) void k_prep(
    const float* __restrict__ w1, const float* __restrict__ w2,
    const float* __restrict__ w3, const float* __restrict__ w4,
    const float* __restrict__ w5,
    unsigned short* __restrict__ wb1, unsigned short* __restrict__ wb2,
    unsigned short* __restrict__ wb3, unsigned short* __restrict__ wb4,
    unsigned short* __restrict__ wb5, unsigned short* __restrict__ zeros,
    const float* __restrict__ pfeat, const float* __restrict__ wup,
    const float* __restrict__ pflow, const float* __restrict__ wuf,
    const float* __restrict__ buf_, float* __restrict__ partial,
    float* __restrict__ feat, unsigned short* __restrict__ featb) {
  __shared__ float wl[1024];
  __shared__ float red[2048];
  const int tid = threadIdx.x;
  const int gblk = blockIdx.x;
  if (gblk < 1188) {
    if (gblk == 0 && tid < 32) zeros[tid] = 0;
    const float* w;
    unsigned short* wb;
    int CIN, COUT, COUTP, IN_OFF, rbase;
    if (gblk < 270)       { w = w1; wb = wb1; CIN = 133; COUT = 48; COUTP = 48; IN_OFF = 136; rbase = 0; }
    else if (gblk < 594)  { w = w2; wb = wb2; CIN = 181; COUT = 48; COUTP = 48; IN_OFF = 88;  rbase = 270; }
    else if (gblk < 882)  { w = w3; wb = wb3; CIN = 229; COUT = 24; COUTP = 32; IN_OFF = 40;  rbase = 594; }
    else if (gblk < 1026) { w = w4; wb = wb4; CIN = 253; COUT = 16; COUTP = 16; IN_OFF = 16;  rbase = 882; }
    else                  { w = w5; wb = wb5; CIN = 269; COUT = 2;  COUTP = 16; IN_OFF = 0;   rbase = 1026; }
    int e = (gblk - rbase) * 256 + tid;
    int nchunk = (CIN + 31) >> 5;
    int TOT = nchunk * 9 * COUTP * 32;
    if (e >= TOT) return;
    int j = e & 7, qpos = (e >> 3) & 3;
    int row = e >> 5;
    int co = row % COUTP;
    int tapch = row / COUTP;
    int tap = tapch % 9, ch = tapch / 9;
    int k = ch * 32 + ((qpos ^ ((co >> 1) & 3)) << 3) + j;
    float v = 0.f;
    if (co < COUT && k < CIN) {
      int ci = featb2ref(IN_OFF + k) - IN_OFF;
      v = w[(co * CIN + ci) * 9 + tap];
    }
    wb[e] = f2b(v);
    return;
  }
  if (gblk >= 4772) {
    int t = (gblk - 4772) * 256 + tid;
    if (t >= B * 2 * HW) return;
    int x = t % W, y = (t / W) % H, co = (t / HW) % 2, b = t / (2 * HW);
    float acc = buf_[co];
    int ky0 = ((y & 1) == 0) ? 1 : 0;
    int kx0 = ((x & 1) == 0) ? 1 : 0;
#pragma unroll
    for (int kyi = 0; kyi < 2; ++kyi) {
      int ky = ky0 + 2 * kyi;
      int iy = (y + 1 - ky) >> 1;
      if (iy < 0 || iy >= H2) continue;
#pragma unroll
      for (int kxi = 0; kxi < 2; ++kxi) {
        int kx = kx0 + 2 * kxi;
        int ix = (x + 1 - kx) >> 1;
        if (ix < 0 || ix >= W2) continue;
#pragma unroll
        for (int ci = 0; ci < 2; ++ci)
          acc += pflow[(b * 2 + ci) * HW2 + iy * W2 + ix] *
                 wuf[((ci * 2 + co) * 4 + ky) * 4 + kx];
      }
    }
    int pix = (b * H + y) * W + x;
    feat[(b * FC + OFF_UF + co) * HW + y * W + x] = acc;
    featb[pix * FCP + OFF_UF + co] = f2b(acc);
    if (co == 0) {
      featb[pix * FCP + 269] = 0;
      featb[pix * FCP + 270] = 0;
      featb[pix * FCP + 271] = 0;
    }
    return;
  }
  int blk = gblk - 1188;
  int chunk = blk % 7, t2 = blk / 7;
  int y2 = t2 % H2, b = t2 / H2;
  int ch0 = chunk * 32;
  for (int i = tid; i < 1024; i += 256) {
    int ci = ch0 + (i >> 5);
    wl[i] = (ci < PFC) ? wup[ci * 32 + (i & 31)] : 0.f;
  }
  __syncthreads();
  int x2 = tid & 63, cg = tid >> 6;
  float acc[8];
#pragma unroll
  for (int v = 0; v < 8; ++v) acc[v] = 0.f;
#pragma unroll 1
  for (int k = 0; k < 8; ++k) {
    int cil = cg * 8 + k;
    int ci = ch0 + cil;
    bool cv = ci < PFC;
    const float* src = pfeat + ((size_t)b * PFC + ci) * HW2;
    float iv[3][3];
#pragma unroll
    for (int dy = -1; dy <= 1; ++dy)
#pragma unroll
      for (int dx = -1; dx <= 1; ++dx) {
        int iy = y2 + dy, ix = x2 + dx;
        float v = 0.f;
        if (cv && iy >= 0 && iy < H2 && ix >= 0 && ix < W2) v = src[iy * W2 + ix];
        iv[dy + 1][dx + 1] = v;
      }
    const float* wc = &wl[cil * 32];
#pragma unroll
    for (int co = 0; co < 2; ++co)
#pragma unroll
      for (int ry = 0; ry < 2; ++ry)
#pragma unroll
        for (int rx = 0; rx < 2; ++rx) {
          float s = acc[co * 4 + ry * 2 + rx];
#pragma unroll
          for (int dy = ry - 1; dy <= ry; ++dy) {
            int ky = 1 + ry - 2 * dy;
#pragma unroll
            for (int dx = rx - 1; dx <= rx; ++dx) {
              int kx = 1 + rx - 2 * dx;
              s += iv[dy + 1][dx + 1] * wc[co * 16 + ky * 4 + kx];
            }
          }
          acc[co * 4 + ry * 2 + rx] = s;
        }
  }
#pragma unroll
  for (int v = 0; v < 8; ++v) red[(cg * 64 + x2) * 8 + v] = acc[v];
  __syncthreads();
  for (int idx = tid; idx < 512; idx += 256) {
    int x2b = idx & 63, vi = idx >> 6;
    float s = red[(0 + x2b) * 8 + vi] + red[(64 + x2b) * 8 + vi] +
              red[(128 + x2b) * 8 + vi] + red[(192 + x2b) * 8 + vi];
    int co = vi >> 2, ry = (vi >> 1) & 1, rx = vi & 1;
    partial[(size_t)chunk * (B * 2 * HW) + (size_t)(b * 2 + co) * HW +
            (2 * y2 + ry) * W + (2 * x2b + rx)] = s;
  }
}

// --------- fused: finalize upfeat (blk<1024) + backwarp (rest) -------------
__global__ __launch_bounds__(256) void k_fin_backwarp(
    const float* __restrict__ partial, const float* __restrict__ bup,
    const float* __restrict__ feat2, float* __restrict__ feat,
    unsigned short* __restrict__ featb, unsigned short* __restrict__ warpedh) {
  int tid = threadIdx.x;
  if (blockIdx.x < 1024) {
    int t = blockIdx.x * 256 + tid;
    float s = 0.f;
#pragma unroll
    for (int c = 0; c < 7; ++c) s += partial[(size_t)c * (B * 2 * HW) + t];
    int rem = t % HW;
    int co = (t / HW) & 1;
    int b = t / (2 * HW);
    s += bup[co];
    feat[((size_t)b * FC + OFF_UPFEAT + co) * HW + rem] = s;
    featb[((size_t)(b * H) * W + rem) * FCP + OFF_UPFEAT + co] = f2b(s);
    return;
  }
  int t = (blockIdx.x - 1024) * 256 + tid;
  if (t >= B * HW) return;
  int x = t % W, y = (t / W) % H, b = t / HW;
  const float SX = 1.25f * (float)W / (float)(W - 1);
  const float SY = 1.25f * (float)H / (float)(H - 1);
  float fx = feat[(b * FC + OFF_UF + 0) * HW + y * W + x];
  float fy = feat[(b * FC + OFF_UF + 1) * HW + y * W + x];
  float px = (float)x + fx * SX;
  float py = (float)y + fy * SY;
  float x0f = floorf(px), y0f = floorf(py);
  int ix0 = (int)x0f, iy0 = (int)y0f;
  float wx1 = px - x0f, wx0 = 1.f - wx1;
  float wy1 = py - y0f, wy0 = 1.f - wy1;
  bool vx0 = (ix0 >= 0) & (ix0 < W), vx1 = (ix0 + 1 >= 0) & (ix0 + 1 < W);
  bool vy0 = (iy0 >= 0) & (iy0 < H), vy1 = (iy0 + 1 >= 0) & (iy0 + 1 < H);
  float w00 = (vx0 && vy0) ? wx0 * wy0 : 0.f;
  float w01 = (vx1 && vy0) ? wx1 * wy0 : 0.f;
  float w10 = (vx0 && vy1) ? wx0 * wy1 : 0.f;
  float w11 = (vx1 && vy1) ? wx1 * wy1 : 0.f;
  float wsum = w00 + w01 + w10 + w11;
  float m = wsum > 0.999f ? 1.f : 0.f;
  w00 *= m; w01 *= m; w10 *= m; w11 *= m;
  int cx0 = min(max(ix0, 0), W - 1), cx1 = min(max(ix0 + 1, 0), W - 1);
  int cy0 = min(max(iy0, 0), H - 1), cy1 = min(max(iy0 + 1, 0), H - 1);
  const float* s = feat2 + b * CF * HW;
  int o00 = cy0 * W + cx0, o01 = cy0 * W + cx1, o10 = cy1 * W + cx0, o11 = cy1 * W + cx1;
#pragma unroll 1
  for (int chunk = 0; chunk < 3; ++chunk) {
    h16x8 out0, out1;
#pragma unroll
    for (int k = 0; k < 16; ++k) {
      const float* sc = s + (chunk * 16 + k) * HW;
      float v = w00 * sc[o00] + w01 * sc[o01] + w10 * sc[o10] + w11 * sc[o11];
      if (k < 8) out0[k & 7] = (_Float16)v;
      else       out1[k & 7] = (_Float16)v;
    }
    h16x8* dst = (h16x8*)(warpedh + ((size_t)chunk * B * HW + t) * 16);
    dst[0] = out0;
    dst[1] = out1;
  }
}

// --------------------------- correlation + leaky ---------------------------
__global__ __launch_bounds__(256) void k_corr(const float* __restrict__ f1,
                                              const unsigned short* __restrict__ warpedh,
                                              const unsigned short* __restrict__ zeros,
                                              float* __restrict__ feat,
                                              unsigned short* __restrict__ featb) {
  __shared__ __align__(16) unsigned short lds[5 * 136 * 16];
  const int swz = ((blockIdx.x & 7) << 8) | (blockIdx.x >> 3);
  const int half = swz & 1;
  const int y = (swz >> 1) & 63, b = swz >> 7;
  const int tid = threadIdx.x;
  const int px = tid >> 1, h = tid & 1;
  const int lane = tid & 63, wv = tid >> 6;
  const int pix = (b * H + y) * W + px;
  const h16x8* hp = (const h16x8*)lds;
  char* ldsc = (char*)lds;
  const float inv = 1.f / 48.f;

  const int R = half ? 4 : 5;
  const int dybase = half ? 5 : 0;
  const int ND = R * 9;
  float acc[45];
#pragma unroll
  for (int d = 0; d < 45; ++d) acc[d] = 0.f;
#pragma unroll 1
  for (int chunk = 0; chunk < 3; ++chunk) {
    __syncthreads();
    const int NQ = R * 136 * 2;
    for (int q0 = 0; q0 < NQ; q0 += 256) {
      int q = q0 + tid;
      if (q < NQ) {
        int pr = q >> 1, u = q & 1;
        int r = pr / 136, p = pr - r * 136;
        int sw = (p >> 2) & 1;
        int yy = y + dybase + r - 4, xx = p - 4;
        const unsigned short* src = zeros;
        if (yy >= 0 && yy < H && xx >= 0 && xx < W)
          src = warpedh + (((size_t)chunk * B * H + b * H + yy) * W + xx) * 16 +
                (u ^ sw) * 8;
        gload16(src, ldsc + (size_t)q0 * 16 + wv * 1024 + lane * 16);
      }
    }
    float av[8];
    const int c0 = chunk * 16 + h * 8;
#pragma unroll
    for (int j = 0; j < 8; ++j)
      av[j] = f1[((size_t)b * CF + c0 + j) * HW + y * W + px];
    h16x2 fh[4];
#pragma unroll
    for (int j = 0; j < 4; ++j) {
      fh[j][0] = (_Float16)av[2 * j];
      fh[j][1] = (_Float16)av[2 * j + 1];
    }
    asm volatile("s_waitcnt vmcnt(0)" ::: "memory");
    __syncthreads();
    if (half == 0) {
#pragma unroll
      for (int j = 0; j < 8; ++j)
        feat[((size_t)b * FC + OFF_F1 + c0 + j) * HW + y * W + px] = av[j];
      uint4 qv;
      qv.x = (unsigned)f2b(av[0]) | ((unsigned)f2b(av[1]) << 16);
      qv.y = (unsigned)f2b(av[2]) | ((unsigned)f2b(av[3]) << 16);
      qv.z = (unsigned)f2b(av[4]) | ((unsigned)f2b(av[5]) << 16);
      qv.w = (unsigned)f2b(av[6]) | ((unsigned)f2b(av[7]) << 16);
      *(uint4*)(featb + (size_t)pix * FCP + FB_F1 + c0) = qv;
    }
#pragma unroll
    for (int dy = 0; dy < 5; ++dy) {
      if (dy < R) {
#pragma unroll
        for (int dx = 0; dx < 9; ++dx) {
          int p = px + dx;
          int sw = (p >> 2) & 1;
          h16x8 v = hp[((dy * 136 + p) << 1) | (h ^ sw)];
          float a = acc[dy * 9 + dx];
          a = __builtin_amdgcn_fdot2((h16x2){v[0], v[1]}, fh[0], a, false);
          a = __builtin_amdgcn_fdot2((h16x2){v[2], v[3]}, fh[1], a, false);
          a = __builtin_amdgcn_fdot2((h16x2){v[4], v[5]}, fh[2], a, false);
          a = __builtin_amdgcn_fdot2((h16x2){v[6], v[7]}, fh[3], a, false);
          acc[dy * 9 + dx] = a;
        }
      }
    }
  }
#pragma unroll
  for (int d = 0; d < 45; ++d) {
    if (d < ND) {
      float s = acc[d] + __shfl_xor(acc[d], 1);
      acc[d] = leaky(s * inv);
    }
  }
  if (h == 0) {
#pragma unroll
    for (int d = 0; d < 45; ++d)
      if (d < ND)
        feat[((size_t)b * FC + OFF_CORR + dybase * 9 + d) * HW + y * W + px] = acc[d];
  } else {
    unsigned short* fb = featb + (size_t)pix * FCP + FB_CORR + dybase * 9;
    if (half == 0) {
#pragma unroll
      for (int g = 0; g < 5; ++g) {
        uint4 qv;
        qv.x = (unsigned)f2b(acc[8 * g + 0]) | ((unsigned)f2b(acc[8 * g + 1]) << 16);
        qv.y = (unsigned)f2b(acc[8 * g + 2]) | ((unsigned)f2b(acc[8 * g + 3]) << 16);
        qv.z = (unsigned)f2b(acc[8 * g + 4]) | ((unsigned)f2b(acc[8 * g + 5]) << 16);
        qv.w = (unsigned)f2b(acc[8 * g + 6]) | ((unsigned)f2b(acc[8 * g + 7]) << 16);
        *(uint4*)(fb + 8 * g) = qv;
      }
#pragma unroll
      for (int d = 40; d < 45; ++d) fb[d] = f2b(acc[d]);
    } else {
      fb[0] = f2b(acc[0]);
      fb[1] = f2b(acc[1]);
      fb[2] = f2b(acc[2]);
#pragma unroll
      for (int g = 0; g < 4; ++g) {
        uint4 qv;
        qv.x = (unsigned)f2b(acc[3 + 8 * g + 0]) | ((unsigned)f2b(acc[3 + 8 * g + 1]) << 16);
        qv.y = (unsigned)f2b(acc[3 + 8 * g + 2]) | ((unsigned)f2b(acc[3 + 8 * g + 3]) << 16);
        qv.z = (unsigned)f2b(acc[3 + 8 * g + 4]) | ((unsigned)f2b(acc[3 + 8 * g + 5]) << 16);
        qv.w = (unsigned)f2b(acc[3 + 8 * g + 6]) | ((unsigned)f2b(acc[3 + 8 * g + 7]) << 16);
        *(uint4*)(fb + 3 + 8 * g) = qv;
      }
      fb[35] = f2b(acc[35]);
    }
  }
}

// --------------- conv3x3 + bias + leaky via MFMA (r5, proven) --------------
// Block = 2 output rows (M=256). 4 waves: wave wv -> out-row wr=wv>>1,
// x-half wc=wv&1 (4 M-frags of 16 px). Stages 4 input rows + weight slab
// per 32-ch chunk via global_load_lds; vmcnt(0)+__syncthreads per chunk.
template <int CIN, int NCHUNK, int COUT, int COUTP, int IN_OFF, int OUT_OFF, bool TO_FLOW>
__global__ __launch_bounds__(256) void k_conv_mfma(
    const unsigned short* __restrict__ featb, const unsigned short* __restrict__ wb,
    const float* __restrict__ bias, const unsigned short* __restrict__ zeros,
    float* __restrict__ fout, unsigned short* __restrict__ bout) {
  constexpr int NF = COUTP / 16;
  constexpr int ROWPX = 144;
  constexpr int IN_ELE = 4 * ROWPX * 32;      // ushorts
  constexpr int W_SLAB = 9 * COUTP * 32;      // ushorts per chunk
  constexpr int NWI = (W_SLAB * 2) / 1024;    // weight gloads per chunk
  constexpr int CLIM = 264 - IN_OFF;

  __shared__ unsigned short lds[IN_ELE + W_SLAB];

  const int swz = ((blockIdx.x & 7) << 6) | (blockIdx.x >> 3);  // 512 blocks
  const int y0 = (swz & 31) * 2, b = swz >> 5;
  const int lane = threadIdx.x & 63, wv = threadIdx.x >> 6;
  const int wr = wv >> 1, wc = wv & 1;
  const int arow = lane & 15, aslc = lane >> 4;

  // input staging descriptors: 9 per wave (i = wv + t*4, 36 total)
  const unsigned short* gp[9];
  int c8a[9];
  int lofs[9];
#pragma unroll
  for (int t = 0; t < 9; ++t) {
    int i = wv + t * 4;
    int r = i / 9, seg = i - r * 9;
    int slot = seg * 16 + (lane >> 2);
    int sub8 = ((lane & 3) ^ ((slot >> 1) & 3)) << 3;
    int yy = y0 + r - 1, xx = slot - 1;
    lofs[t] = (r * ROWPX + seg * 16) * 64;
    gp[t] = zeros; c8a[t] = 1 << 20;
    if (yy >= 0 && yy < H && xx >= 0 && xx < W) {
      gp[t] = featb + ((b * H + yy) * W + xx) * FCP + IN_OFF + sub8;
      c8a[t] = sub8;
    }
  }

  int a_off[4][3];
#pragma unroll
  for (int mi = 0; mi < 4; ++mi)
#pragma unroll
    for (int kx = 0; kx < 3; ++kx) {
      int slot = (wc * 4 + mi) * 16 + arow + kx;
      a_off[mi][kx] = slot * 32 + ((aslc ^ ((slot >> 1) & 3)) << 3);
    }
  int b_off[NF];
#pragma unroll
  for (int nf = 0; nf < NF; ++nf) {
    int co = nf * 16 + arow;
    b_off[nf] = IN_ELE + co * 32 + ((aslc ^ ((co >> 1) & 3)) << 3);
  }

  f32x4 acc[4][NF];
#pragma unroll
  for (int mi = 0; mi < 4; ++mi)
#pragma unroll
    for (int nf = 0; nf < NF; ++nf) acc[mi][nf] = (f32x4){0.f, 0.f, 0.f, 0.f};

  char* ldsc = (char*)lds;

  for (int ch = 0; ch < NCHUNK; ++ch) {
    const int ci0 = ch * 32;
    __syncthreads();
#pragma unroll
    for (int t = 0; t < 9; ++t) {
      const unsigned short* g = (c8a[t] + ci0 <= CLIM) ? gp[t] + ci0 : zeros;
      gload16(g, ldsc + lofs[t]);
    }
    for (int wi = wv; wi < NWI; wi += 4)
      gload16(wb + (size_t)ch * W_SLAB + wi * 512 + lane * 8,
              ldsc + IN_ELE * 2 + wi * 1024);
    asm volatile("s_waitcnt vmcnt(0)" ::: "memory");
    __syncthreads();
#pragma unroll
    for (int ky = 0; ky < 3; ++ky) {
#pragma unroll
      for (int kx = 0; kx < 3; ++kx) {
        bf16x8 afr[4];
#pragma unroll
        for (int mi = 0; mi < 4; ++mi)
          afr[mi] = *(const bf16x8*)(lds + a_off[mi][kx] + (wr + ky) * (ROWPX * 32));
#pragma unroll
        for (int nf = 0; nf < NF; ++nf) {
          bf16x8 bfr = *(const bf16x8*)(lds + b_off[nf] + (ky * 3 + kx) * (COUTP * 32));
#pragma unroll
          for (int mi = 0; mi < 4; ++mi)
            acc[mi][nf] = __builtin_amdgcn_mfma_f32_16x16x32_bf16(
                afr[mi], bfr, acc[mi][nf], 0, 0, 0);
        }
      }
    }
  }

  const int dcol = lane & 15;
  const int yout = y0 + wr;
#pragma unroll
  for (int nf = 0; nf < NF; ++nf) {
    int co = nf * 16 + dcol;
    if (co < COUT) {
      float bv = bias[co];
#pragma unroll
      for (int mi = 0; mi < 4; ++mi) {
#pragma unroll
        for (int r = 0; r < 4; ++r) {
          int pixel = (wc * 4 + mi) * 16 + (lane >> 4) * 4 + r;
          float v = leaky(acc[mi][nf][r] + bv);
          if constexpr (TO_FLOW) {
            fout[(b * 2 + co) * HW + yout * W + pixel] = v;
          } else {
            fout[(b * FC + OUT_OFF + co) * HW + yout * W + pixel] = v;
            bout[((b * H + yout) * W + pixel) * FCP + OUT_OFF + co] = f2b(v);
          }
        }
      }
    }
  }
}

// ---------------------------------------------------------------------------
extern "C" void kernel_launch(void* const* d_in, const int* in_sizes, int n_in,
                              void* d_out, int out_size, void* d_ws, size_t ws_size,
                              hipStream_t stream) {
  (void)in_sizes; (void)n_in; (void)out_size; (void)ws_size;
  const float* feat_1 = (const float*)d_in[0];
  const float* feat_2 = (const float*)d_in[1];
  const float* prev_flow = (const float*)d_in[2];
  const float* prev_feat = (const float*)d_in[3];
  const float* w1 = (const float*)d_in[4];
  const float* b1 = (const float*)d_in[5];
  const float* w2 = (const float*)d_in[6];
  const float* b2 = (const float*)d_in[7];
  const float* w3 = (const float*)d_in[8];
  const float* b3 = (const float*)d_in[9];
  const float* w4 = (const float*)d_in[10];
  const float* b4 = (const float*)d_in[11];
  const float* w5 = (const float*)d_in[12];
  const float* b5 = (const float*)d_in[13];
  const float* w_upflow = (const float*)d_in[14];
  const float* b_upflow = (const float*)d_in[15];
  const float* w_upfeat = (const float*)d_in[16];
  const float* b_upfeat = (const float*)d_in[17];

  float* out = (float*)d_out;
  float* feat = out + FLOW_ELEMS;

  char* ws = (char*)d_ws;
  unsigned short* zeros = (unsigned short*)(ws + WS_ZEROS);
  unsigned short* featb = (unsigned short*)(ws + WS_FEATB);
  unsigned short* warpedh = (unsigned short*)(ws + WS_WARPEDH);
  float* partial = (float*)(ws + WS_PART);
  unsigned short* wb1 = (unsigned short*)(ws + WS_WB);
  unsigned short* wb2 = wb1 + 5 * 9 * 48 * 32;
  unsigned short* wb3 = wb2 + 6 * 9 * 48 * 32;
  unsigned short* wb4 = wb3 + 8 * 9 * 32 * 32;
  unsigned short* wb5 = wb4 + 8 * 9 * 16 * 32;

  k_prep<<<1188 + 3584 + 1024, 256, 0, stream>>>(
      w1, w2, w3, w4, w5, wb1, wb2, wb3, wb4, wb5, zeros,
      prev_feat, w_upfeat, prev_flow, w_upflow, b_upflow, partial, feat, featb);
  k_fin_backwarp<<<1024 + 512, 256, 0, stream>>>(partial, b_upfeat, feat_2,
                                                 feat, featb, warpedh);
  k_corr<<<B * H * 2, 256, 0, stream>>>(feat_1, warpedh, zeros, feat, featb);

  k_conv_mfma<133, 5, 48, 48, 136, 88, false><<<512, 256, 0, stream>>>(featb, wb1, b1, zeros, feat, featb);
  k_conv_mfma<181, 6, 48, 48, 88, 40, false><<<512, 256, 0, stream>>>(featb, wb2, b2, zeros, feat, featb);
  k_conv_mfma<229, 8, 24, 32, 40, 16, false><<<512, 256, 0, stream>>>(featb, wb3, b3, zeros, feat, featb);
  k_conv_mfma<253, 8, 16, 16, 16, 0, false><<<512, 256, 0, stream>>>(featb, wb4, b4, zeros, feat, featb);
  k_conv_mfma<269, 9, 2, 16, 0, 0, true><<<512, 256, 0, stream>>>(featb, wb5, b5, zeros, out, nullptr);
}